// Round 1
// baseline (522.326 us; speedup 1.0000x reference)
//
#include <hip/hip_runtime.h>
#include <hip/hip_bf16.h>
#include <cstdint>
#include <cstddef>

typedef unsigned short u16;
typedef __bf16 bf16x8 __attribute__((ext_vector_type(8)));
typedef float f32x4 __attribute__((ext_vector_type(4)));

#define IN_F   4096
#define OUT_F  4096
#define IC_N   409      // int(4096*0.1)
#define K_NON  3687     // 4096-409
#define K_NONP 3712     // 58*64 (pad, BK-aligned sigmoid boundary)
#define K_HI0  3712     // a_hi * w_hi
#define K_LO0  4121     // a_lo * w_hi
#define K_HI1  4530     // a_hi * w_lo
#define K_END  4939
#define K_TOT  4992     // 78*64
#define BATCHN 8192

#define KT_ITERS 78
#define KT_SPLIT 58

__device__ __forceinline__ u16 f2bf(float f) {          // RNE fp32->bf16
  uint32_t u = __float_as_uint(f);
  uint32_t r = (u + 0x7FFFu + ((u >> 16) & 1u)) >> 16;
  return (u16)r;
}
__device__ __forceinline__ float bf2f(u16 h) {
  return __uint_as_float(((uint32_t)h) << 16);
}
__device__ __forceinline__ float coefj(int j) {
  return (j == 0 || j == IC_N - 1) ? 1.0f : 2.0f;
}

// ---------------- packing: A = [bf16(x_nc) | 0 | hi(xc*c) | lo(xc*c) | hi(xc*c) | 0]
__global__ void pack_a_kernel(const float* __restrict__ x, u16* __restrict__ Ab) {
  const int units = BATCHN * (K_TOT / 8);
  for (int u = blockIdx.x * blockDim.x + threadIdx.x; u < units;
       u += gridDim.x * blockDim.x) {
    const int row = u / (K_TOT / 8);
    const int kb  = (u % (K_TOT / 8)) * 8;
    u16 tmp[8] __attribute__((aligned(16)));
#pragma unroll
    for (int e = 0; e < 8; ++e) {
      const int k = kb + e;
      u16 o;
      if (k < K_NON) {
        o = f2bf(x[(size_t)row * IN_F + IC_N + k]);
      } else if (k < K_HI0) {
        o = 0;
      } else if (k < K_LO0) {
        const int j = k - K_HI0;
        o = f2bf(x[(size_t)row * IN_F + j] * coefj(j));
      } else if (k < K_HI1) {
        const int j = k - K_LO0;
        const float v = x[(size_t)row * IN_F + j] * coefj(j);
        const u16 h = f2bf(v);
        o = f2bf(v - bf2f(h));
      } else if (k < K_END) {
        const int j = k - K_HI1;
        o = f2bf(x[(size_t)row * IN_F + j] * coefj(j));
      } else {
        o = 0;
      }
      tmp[e] = o;
    }
    *(int4*)(Ab + (size_t)row * K_TOT + kb) = *(const int4*)tmp;
  }
}

// ---------------- packing: B = [bf16(W_non) | 0 | hi(W_nmda) | hi(W_nmda) | lo(W_nmda) | 0]
__global__ void pack_b_kernel(const float* __restrict__ Wnon,
                              const float* __restrict__ Wnmda,
                              u16* __restrict__ Bb) {
  const int units = OUT_F * (K_TOT / 8);
  for (int u = blockIdx.x * blockDim.x + threadIdx.x; u < units;
       u += gridDim.x * blockDim.x) {
    const int row = u / (K_TOT / 8);
    const int kb  = (u % (K_TOT / 8)) * 8;
    u16 tmp[8] __attribute__((aligned(16)));
#pragma unroll
    for (int e = 0; e < 8; ++e) {
      const int k = kb + e;
      u16 o;
      if (k < K_NON) {
        o = f2bf(Wnon[(size_t)row * K_NON + k]);
      } else if (k < K_HI0) {
        o = 0;
      } else if (k < K_LO0) {
        o = f2bf(Wnmda[(size_t)row * IC_N + (k - K_HI0)]);
      } else if (k < K_HI1) {
        o = f2bf(Wnmda[(size_t)row * IC_N + (k - K_LO0)]);
      } else if (k < K_END) {
        const float v = Wnmda[(size_t)row * IC_N + (k - K_HI1)];
        const u16 h = f2bf(v);
        o = f2bf(v - bf2f(h));
      } else {
        o = 0;
      }
      tmp[e] = o;
    }
    *(int4*)(Bb + (size_t)row * K_TOT + kb) = *(const int4*)tmp;
  }
}

// ---------------- fused GEMM (m97 structure: 128x128 tile, BK=64, 4 waves, global_load_lds w16)
#define GLOAD_LDS16(g, l)                                         \
  __builtin_amdgcn_global_load_lds(                               \
      (const __attribute__((address_space(1))) void*)(g),         \
      (__attribute__((address_space(3))) void*)(l), 16, 0, 0)

__global__ __launch_bounds__(256) void gemm_fused_kernel(
    const u16* __restrict__ Ab, const u16* __restrict__ Bb,
    const float* __restrict__ bnon, float* __restrict__ out) {
  __shared__ u16 As[128 * 64];
  __shared__ u16 Bs[128 * 64];

  const int bx = blockIdx.x;
  const int bm = bx >> 5;        // 64 row-blocks
  const int bn = bx & 31;        // 32 col-blocks
  const int rowBase = bm * 128;
  const int colBase = bn * 128;

  const int tid  = threadIdx.x;
  const int w    = tid >> 6;
  const int lane = tid & 63;
  const int wm = w >> 1, wn = w & 1;
  const int wRow = wm * 64, wCol = wn * 64;
  const int l15 = lane & 15;
  const int ko  = (lane >> 4) * 8;

  f32x4 acc[4][4] = {};

  // bias for the mid-loop sigmoid transform (per-lane column values)
  float bn4[4];
#pragma unroll
  for (int n = 0; n < 4; ++n) bn4[n] = bnon[colBase + wCol + n * 16 + l15];

  // staging addresses: issue i covers tile rows i*32 + w*8 + (lane>>3), cols (lane&7)*8
  const u16* aBase = Ab + (size_t)(rowBase + w * 8 + (lane >> 3)) * K_TOT + (lane & 7) * 8;
  const u16* bBase = Bb + (size_t)(colBase + w * 8 + (lane >> 3)) * K_TOT + (lane & 7) * 8;
  u16* aLds = As + w * 512 + lane * 8;
  u16* bLds = Bs + w * 512 + lane * 8;

  for (int kt = 0; kt < KT_ITERS; ++kt) {
    __syncthreads();  // previous tile fully consumed before overwrite
    const int kOff = kt * 64;
#pragma unroll
    for (int i = 0; i < 4; ++i) {
      GLOAD_LDS16(aBase + (size_t)(i * 32) * K_TOT + kOff, aLds + i * 2048);
      GLOAD_LDS16(bBase + (size_t)(i * 32) * K_TOT + kOff, bLds + i * 2048);
    }
    __syncthreads();  // drains vmcnt(0): tile resident

    if (kt == KT_SPLIT) {
      // acc == x_nc @ W_non^T ; transform in place: sigmoid(acc + b) - 1
#pragma unroll
      for (int n = 0; n < 4; ++n) {
        const float b = bn4[n];
#pragma unroll
        for (int m = 0; m < 4; ++m) {
#pragma unroll
          for (int j = 0; j < 4; ++j) {
            const float t = acc[m][n][j] + b;
            const float e = __expf(-t);
            acc[m][n][j] = 1.0f / (1.0f + e) - 1.0f;
          }
        }
      }
    }

#pragma unroll
    for (int kk = 0; kk < 64; kk += 32) {
      bf16x8 af[4], bf[4];
#pragma unroll
      for (int m = 0; m < 4; ++m)
        af[m] = *(const bf16x8*)(As + (wRow + m * 16 + l15) * 64 + kk + ko);
#pragma unroll
      for (int n = 0; n < 4; ++n)
        bf[n] = *(const bf16x8*)(Bs + (wCol + n * 16 + l15) * 64 + kk + ko);
#pragma unroll
      for (int m = 0; m < 4; ++m)
#pragma unroll
        for (int n = 0; n < 4; ++n)
          acc[m][n] = __builtin_amdgcn_mfma_f32_16x16x32_bf16(af[m], bf[n], acc[m][n], 0, 0, 0);
    }
  }

  // epilogue: Hill function, C/D layout col=lane&15, row=(lane>>4)*4+j  [m89/m91]
#pragma unroll
  for (int m = 0; m < 4; ++m) {
#pragma unroll
    for (int n = 0; n < 4; ++n) {
#pragma unroll
      for (int j = 0; j < 4; ++j) {
        const int r = rowBase + wRow + m * 16 + (lane >> 4) * 4 + j;
        const int c = colBase + wCol + n * 16 + l15;
        const float pre = acc[m][n][j];
        const float xn = pre * pre;
        out[(size_t)r * OUT_F + c] = xn / (0.25f + xn);
      }
    }
  }
}

// ---------------- fallback (only if workspace too small): naive fp32, correct but slow
__global__ void naive_fused_kernel(const float* __restrict__ x,
                                   const float* __restrict__ Wnmda,
                                   const float* __restrict__ Wnon,
                                   const float* __restrict__ bnon,
                                   float* __restrict__ out) {
  const long long total = (long long)BATCHN * OUT_F;
  for (long long idx = (long long)blockIdx.x * blockDim.x + threadIdx.x;
       idx < total; idx += (long long)gridDim.x * blockDim.x) {
    const int b = (int)(idx / OUT_F);
    const int o = (int)(idx % OUT_F);
    float s = bnon[o];
    for (int k = 0; k < K_NON; ++k)
      s += x[(size_t)b * IN_F + IC_N + k] * Wnon[(size_t)o * K_NON + k];
    const float state = 1.0f / (1.0f + __expf(-s)) - 1.0f;
    float ca = 0.0f;
    for (int j = 0; j < IC_N; ++j)
      ca += x[(size_t)b * IN_F + j] * coefj(j) * Wnmda[(size_t)o * IC_N + j];
    const float pre = ca + state;
    const float xn = pre * pre;
    out[idx] = xn / (0.25f + xn);
  }
}

extern "C" void kernel_launch(void* const* d_in, const int* in_sizes, int n_in,
                              void* d_out, int out_size, void* d_ws, size_t ws_size,
                              hipStream_t stream) {
  const float* x     = (const float*)d_in[0];
  const float* Wnmda = (const float*)d_in[1];
  const float* Wnon  = (const float*)d_in[2];
  const float* bnon  = (const float*)d_in[3];
  float* out = (float*)d_out;

  const size_t needA = (size_t)BATCHN * K_TOT * sizeof(u16);  // ~81.8 MB
  const size_t needB = (size_t)OUT_F * K_TOT * sizeof(u16);   // ~40.9 MB

  if (ws_size < needA + needB) {
    naive_fused_kernel<<<8192, 256, 0, stream>>>(x, Wnmda, Wnon, bnon, out);
    return;
  }

  u16* Ab = (u16*)d_ws;
  u16* Bb = Ab + (size_t)BATCHN * K_TOT;

  pack_a_kernel<<<2048, 256, 0, stream>>>(x, Ab);
  pack_b_kernel<<<1024, 256, 0, stream>>>(Wnon, Wnmda, Bb);
  gemm_fused_kernel<<<64 * 32, 256, 0, stream>>>(Ab, Bb, bnon, out);
}

// Round 3
// 451.304 us; speedup vs baseline: 1.1574x; 1.1574x over previous
//
#include <hip/hip_runtime.h>
#include <hip/hip_bf16.h>
#include <cstdint>
#include <cstddef>

typedef unsigned short u16;
typedef __bf16 bf16x8 __attribute__((ext_vector_type(8)));
typedef float f32x4 __attribute__((ext_vector_type(4)));

#define IN_F   4096
#define OUT_F  4096
#define IC_N   409      // int(4096*0.1)
#define K_NON  3687     // 4096-409
#define K_HI0  3712     // 58*64: sigmoid boundary (BK-aligned)
#define K_LO0  4121
#define K_HI1  4530
#define K_END  4939
#define K_TOT  4992     // 78*64
#define BATCHN 8192
#define NT     78       // K-tiles of 64
#define T_SPLIT 58      // body index where state transform applies

__device__ __forceinline__ u16 f2bf(float f) {          // RNE fp32->bf16
  uint32_t u = __float_as_uint(f);
  uint32_t r = (u + 0x7FFFu + ((u >> 16) & 1u)) >> 16;
  return (u16)r;
}
__device__ __forceinline__ float bf2f(u16 h) {
  return __uint_as_float(((uint32_t)h) << 16);
}
__device__ __forceinline__ float coefj(int j) {
  return (j == 0 || j == IC_N - 1) ? 1.0f : 2.0f;
}

// ---------------- packing: A = [bf16(x_nc) | 0 | hi(xc*c) | lo(xc*c) | hi(xc*c) | 0]
__global__ void pack_a_kernel(const float* __restrict__ x, u16* __restrict__ Ab) {
  const int units = BATCHN * (K_TOT / 8);
  for (int u = blockIdx.x * blockDim.x + threadIdx.x; u < units;
       u += gridDim.x * blockDim.x) {
    const int row = u / (K_TOT / 8);
    const int kb  = (u % (K_TOT / 8)) * 8;
    u16 tmp[8] __attribute__((aligned(16)));
#pragma unroll
    for (int e = 0; e < 8; ++e) {
      const int k = kb + e;
      u16 o;
      if (k < K_NON) {
        o = f2bf(x[(size_t)row * IN_F + IC_N + k]);
      } else if (k < K_HI0) {
        o = 0;
      } else if (k < K_LO0) {
        const int j = k - K_HI0;
        o = f2bf(x[(size_t)row * IN_F + j] * coefj(j));
      } else if (k < K_HI1) {
        const int j = k - K_LO0;
        const float v = x[(size_t)row * IN_F + j] * coefj(j);
        const u16 h = f2bf(v);
        o = f2bf(v - bf2f(h));
      } else if (k < K_END) {
        const int j = k - K_HI1;
        o = f2bf(x[(size_t)row * IN_F + j] * coefj(j));
      } else {
        o = 0;
      }
      tmp[e] = o;
    }
    *(int4*)(Ab + (size_t)row * K_TOT + kb) = *(const int4*)tmp;
  }
}

// ---------------- packing: B = [bf16(W_non) | 0 | hi(W_nmda) | hi(W_nmda) | lo(W_nmda) | 0]
__global__ void pack_b_kernel(const float* __restrict__ Wnon,
                              const float* __restrict__ Wnmda,
                              u16* __restrict__ Bb) {
  const int units = OUT_F * (K_TOT / 8);
  for (int u = blockIdx.x * blockDim.x + threadIdx.x; u < units;
       u += gridDim.x * blockDim.x) {
    const int row = u / (K_TOT / 8);
    const int kb  = (u % (K_TOT / 8)) * 8;
    u16 tmp[8] __attribute__((aligned(16)));
#pragma unroll
    for (int e = 0; e < 8; ++e) {
      const int k = kb + e;
      u16 o;
      if (k < K_NON) {
        o = f2bf(Wnon[(size_t)row * K_NON + k]);
      } else if (k < K_HI0) {
        o = 0;
      } else if (k < K_LO0) {
        o = f2bf(Wnmda[(size_t)row * IC_N + (k - K_HI0)]);
      } else if (k < K_HI1) {
        o = f2bf(Wnmda[(size_t)row * IC_N + (k - K_LO0)]);
      } else if (k < K_END) {
        const float v = Wnmda[(size_t)row * IC_N + (k - K_HI1)];
        const u16 h = f2bf(v);
        o = f2bf(v - bf2f(h));
      } else {
        o = 0;
      }
      tmp[e] = o;
    }
    *(int4*)(Bb + (size_t)row * K_TOT + kb) = *(const int4*)tmp;
  }
}

// ---------------- fused GEMM: 256x256 tile, BK=64, 8 waves, 8-phase counted-vmcnt pipeline
#define GLOAD16(gp, lp)                                           \
  __builtin_amdgcn_global_load_lds(                               \
      (const __attribute__((address_space(1))) void*)(gp),        \
      (__attribute__((address_space(3))) void*)(lp), 16, 0, 0)

#define MEMFENCE() asm volatile("" ::: "memory")
#define BAR() do { MEMFENCE(); __builtin_amdgcn_s_barrier(); MEMFENCE(); } while (0)

// One phase: (BW = buffer, KK = k-half slot, MH = m-half). 8 or 4 ds_read_b128,
// stage one 16KB slot (2 gloads), barrier, lgkm drain, 16 MFMA under setprio.
// VMW: 0 = none, 1 = counted vmcnt before the closing barrier.
#define PHASE(BW, KK, MH, STAGE_STMT, VMW) do {                               \
    if ((MH) == 0) {                                                          \
      _Pragma("unroll")                                                       \
      for (int n = 0; n < 4; ++n)                                             \
        bfr[n] = *(const bf16x8*)(LDSc + (BW) * 65536 + 32768 +               \
                  (KK) * 16384 + (wCol + n * 16) * 64 + laneOff);             \
    }                                                                         \
    bf16x8 af[4];                                                             \
    _Pragma("unroll")                                                         \
    for (int mm = 0; mm < 4; ++mm)                                            \
      af[mm] = *(const bf16x8*)(LDSc + (BW) * 65536 +                         \
                (KK) * 16384 + (wRow + (MH) * 64 + mm * 16) * 64 + laneOff);  \
    STAGE_STMT;                                                               \
    BAR();                                                                    \
    asm volatile("s_waitcnt lgkmcnt(0)" ::: "memory");                        \
    __builtin_amdgcn_sched_barrier(0);                                        \
    __builtin_amdgcn_s_setprio(1);                                            \
    _Pragma("unroll")                                                         \
    for (int mm = 0; mm < 4; ++mm)                                            \
      _Pragma("unroll")                                                       \
      for (int n = 0; n < 4; ++n)                                             \
        acc[(MH) * 4 + mm][n] = __builtin_amdgcn_mfma_f32_16x16x32_bf16(      \
            af[mm], bfr[n], acc[(MH) * 4 + mm][n], 0, 0, 0);                  \
    __builtin_amdgcn_s_setprio(0);                                            \
    if (VMW) {                                                                \
      if (T + 2 < NT) asm volatile("s_waitcnt vmcnt(4)" ::: "memory");        \
      else            asm volatile("s_waitcnt vmcnt(0)" ::: "memory");        \
    }                                                                         \
    BAR();                                                                    \
  } while (0)

__global__ __launch_bounds__(512, 1) void gemm_fused_kernel(
    const u16* __restrict__ Ab, const u16* __restrict__ Bb,
    const float* __restrict__ bnon, float* __restrict__ out) {
  // 8 slots of 16 KB: [buf][mat A/B][k-half]. Slot = 256 rows x 32 bf16.
  // phys = pair*128B + ((((row&1)<<2)|chunk16) ^ (pair&7))*16B  (involution)
  __shared__ __attribute__((aligned(16))) u16 LDSu[65536];
  char* LDSc = (char*)LDSu;

  const int bid = blockIdx.x;
  const int swz = ((bid & 7) << 6) | (bid >> 3);   // 512 % 8 == 0: bijective XCD swizzle
  const int bm = swz >> 4, bn = swz & 15;
  const int rowBase = bm * 256, colBase = bn * 256;

  const int tid  = threadIdx.x;
  const int w    = tid >> 6, lane = tid & 63;
  const int wm = w >> 2, wn = w & 3;               // 2 x 4 wave grid
  const int wRow = wm * 128, wCol = wn * 64;       // per-wave 128x64 output
  const int l15 = lane & 15, g = lane >> 4;

  // per-lane swizzled read offset (constant across fragments; R*64 adds cleanly)
  const int laneOff = ((l15 >> 1) << 7) +
                      (((((l15 & 1) << 2) | g) ^ ((l15 >> 1) & 7)) << 4);

  // staging: linear LDS dest (d = issue*8192 + tid*16), inverse-swizzled global src
  int rowS[2], colS[2];
#pragma unroll
  for (int is = 0; is < 2; ++is) {
    const int d = is * 8192 + tid * 16;
    const int b = d ^ ((d >> 3) & 0x70);
    rowS[is] = ((b >> 7) << 1) | ((b >> 6) & 1);
    colS[is] = (b >> 1) & 31;
  }
  const u16* pA0 = Ab + (size_t)(rowBase + rowS[0]) * K_TOT + colS[0];
  const u16* pA1 = Ab + (size_t)(rowBase + rowS[1]) * K_TOT + colS[1];
  const u16* pB0 = Bb + (size_t)(colBase + rowS[0]) * K_TOT + colS[0];
  const u16* pB1 = Bb + (size_t)(colBase + rowS[1]) * K_TOT + colS[1];

  // bias: load and force-retire so the vmcnt ledger stays clean
  float bn4[4];
#pragma unroll
  for (int n = 0; n < 4; ++n) bn4[n] = bnon[colBase + wCol + n * 16 + l15];
  asm volatile("" :: "v"(bn4[0]), "v"(bn4[1]), "v"(bn4[2]), "v"(bn4[3]));

  auto stage = [&](int buf, int mat, int ks, int tile) {
    if (tile < NT) {
      const u16* s0 = (mat ? pB0 : pA0) + tile * 64 + ks * 32;
      const u16* s1 = (mat ? pB1 : pA1) + tile * 64 + ks * 32;
      char* dst = LDSc + buf * 65536 + mat * 32768 + ks * 16384 + tid * 16;
      GLOAD16(s0, dst);
      GLOAD16(s1, dst + 8192);
    }
  };

  f32x4 acc[8][4] = {};
  bf16x8 bfr[4];

  // prologue: tile 0 full (buf0), tile 1 k-half0 (buf1); A-k1/B-k1 of tile 1
  // are issued by body 0's phases 0/1.
  stage(0, 0, 0, 0); stage(0, 1, 0, 0); stage(0, 0, 1, 0); stage(0, 1, 1, 0);
  stage(1, 0, 0, 1); stage(1, 1, 0, 1);
  asm volatile("s_waitcnt vmcnt(4)" ::: "memory");   // tile 0 resident (oldest 8 of 12)
  BAR();

  for (int T = 0; T < NT; T += 2) {
    if (T == T_SPLIT) {
      // acc == x_nc @ W_non^T complete; in-place: sigmoid(acc+b) - 1
#pragma unroll
      for (int m = 0; m < 8; ++m)
#pragma unroll
        for (int n = 0; n < 4; ++n)
#pragma unroll
          for (int j = 0; j < 4; ++j) {
            const float t = acc[m][n][j] + bn4[n];
            acc[m][n][j] = 1.0f / (1.0f + __expf(-t)) - 1.0f;
          }
    }
    // window tile T from buf0 (phases 0-3), tile T+1 from buf1 (phases 4-7).
    // Refill ledger (slot dies -> issue next phase; land checked by vmcnt(4)):
    PHASE(0, 0, 0, stage(1, 0, 1, T + 1), 0);  // issue buf1.A-k1 (tile T+1)
    PHASE(0, 0, 1, stage(1, 1, 1, T + 1), 0);  // issue buf1.B-k1 (tile T+1)
    PHASE(0, 1, 0, stage(0, 0, 0, T + 2), 0);  // buf0.A-k0 died @p1 -> tile T+2
    PHASE(0, 1, 1, stage(0, 1, 0, T + 2), 1);  // buf0.B-k0 -> tile T+2 ; vmcnt
    PHASE(1, 0, 0, stage(0, 0, 1, T + 2), 0);  // buf0.A-k1 died @p3 -> tile T+2
    PHASE(1, 0, 1, stage(0, 1, 1, T + 2), 0);  // buf0.B-k1 -> tile T+2
    PHASE(1, 1, 0, stage(1, 0, 0, T + 3), 0);  // buf1.A-k0 died @p5 -> tile T+3
    PHASE(1, 1, 1, stage(1, 1, 0, T + 3), 1);  // buf1.B-k0 -> tile T+3 ; vmcnt
  }

  // epilogue: Hill. C/D layout col=lane&15, row=(lane>>4)*4+j  [m89/m91]
#pragma unroll
  for (int m = 0; m < 8; ++m) {
#pragma unroll
    for (int n = 0; n < 4; ++n) {
#pragma unroll
      for (int j = 0; j < 4; ++j) {
        const int r = rowBase + wRow + m * 16 + g * 4 + j;
        const int c = colBase + wCol + n * 16 + l15;
        const float pre = acc[m][n][j];
        const float xn = pre * pre;
        out[(size_t)r * OUT_F + c] = xn / (0.25f + xn);
      }
    }
  }
}

// ---------------- fallback (workspace too small): naive fp32
__global__ void naive_fused_kernel(const float* __restrict__ x,
                                   const float* __restrict__ Wnmda,
                                   const float* __restrict__ Wnon,
                                   const float* __restrict__ bnon,
                                   float* __restrict__ out) {
  const long long total = (long long)BATCHN * OUT_F;
  for (long long idx = (long long)blockIdx.x * blockDim.x + threadIdx.x;
       idx < total; idx += (long long)gridDim.x * blockDim.x) {
    const int b = (int)(idx / OUT_F);
    const int o = (int)(idx % OUT_F);
    float s = bnon[o];
    for (int k = 0; k < K_NON; ++k)
      s += x[(size_t)b * IN_F + IC_N + k] * Wnon[(size_t)o * K_NON + k];
    const float state = 1.0f / (1.0f + __expf(-s)) - 1.0f;
    float ca = 0.0f;
    for (int j = 0; j < IC_N; ++j)
      ca += x[(size_t)b * IN_F + j] * coefj(j) * Wnmda[(size_t)o * IC_N + j];
    const float pre = ca + state;
    const float xn = pre * pre;
    out[idx] = xn / (0.25f + xn);
  }
}

extern "C" void kernel_launch(void* const* d_in, const int* in_sizes, int n_in,
                              void* d_out, int out_size, void* d_ws, size_t ws_size,
                              hipStream_t stream) {
  const float* x     = (const float*)d_in[0];
  const float* Wnmda = (const float*)d_in[1];
  const float* Wnon  = (const float*)d_in[2];
  const float* bnon  = (const float*)d_in[3];
  float* out = (float*)d_out;

  const size_t needA = (size_t)BATCHN * K_TOT * sizeof(u16);  // ~81.8 MB
  const size_t needB = (size_t)OUT_F * K_TOT * sizeof(u16);   // ~40.9 MB

  if (ws_size < needA + needB) {
    naive_fused_kernel<<<8192, 256, 0, stream>>>(x, Wnmda, Wnon, bnon, out);
    return;
  }

  u16* Ab = (u16*)d_ws;
  u16* Bb = Ab + (size_t)BATCHN * K_TOT;

  pack_a_kernel<<<2048, 256, 0, stream>>>(x, Ab);
  pack_b_kernel<<<1024, 256, 0, stream>>>(Wnon, Wnmda, Bb);
  gemm_fused_kernel<<<512, 512, 0, stream>>>(Ab, Bb, bnon, out);
}

// Round 4
// 436.410 us; speedup vs baseline: 1.1969x; 1.0341x over previous
//
#include <hip/hip_runtime.h>
#include <hip/hip_bf16.h>
#include <cstdint>
#include <cstddef>

typedef unsigned short u16;
typedef __bf16 bf16x8 __attribute__((ext_vector_type(8)));
typedef float f32x4 __attribute__((ext_vector_type(4)));

#define IN_F   4096
#define OUT_F  4096
#define IC_N   409      // int(4096*0.1)
#define K_NON  3687     // 4096-409
#define K_HI0  3712     // 58*64: sigmoid boundary (BK-aligned)
#define K_LO0  4121
#define K_HI1  4530
#define K_END  4939
#define K_TOT  4992     // 78*64
#define BATCHN 8192
#define NT     78       // K-tiles of 64
#define T_SPLIT 58      // body index where state transform applies

__device__ __forceinline__ u16 f2bf(float f) {          // RNE fp32->bf16
  uint32_t u = __float_as_uint(f);
  uint32_t r = (u + 0x7FFFu + ((u >> 16) & 1u)) >> 16;
  return (u16)r;
}
__device__ __forceinline__ float bf2f(u16 h) {
  return __uint_as_float(((uint32_t)h) << 16);
}
__device__ __forceinline__ float coefj(int j) {
  return (j == 0 || j == IC_N - 1) ? 1.0f : 2.0f;
}

// ---------------- packing: A = [bf16(x_nc) | 0 | hi(xc*c) | lo(xc*c) | hi(xc*c) | 0]
__global__ void pack_a_kernel(const float* __restrict__ x, u16* __restrict__ Ab) {
  const int units = BATCHN * (K_TOT / 8);
  for (int u = blockIdx.x * blockDim.x + threadIdx.x; u < units;
       u += gridDim.x * blockDim.x) {
    const int row = u / (K_TOT / 8);
    const int kb  = (u % (K_TOT / 8)) * 8;
    u16 tmp[8] __attribute__((aligned(16)));
#pragma unroll
    for (int e = 0; e < 8; ++e) {
      const int k = kb + e;
      u16 o;
      if (k < K_NON) {
        o = f2bf(x[(size_t)row * IN_F + IC_N + k]);
      } else if (k < K_HI0) {
        o = 0;
      } else if (k < K_LO0) {
        const int j = k - K_HI0;
        o = f2bf(x[(size_t)row * IN_F + j] * coefj(j));
      } else if (k < K_HI1) {
        const int j = k - K_LO0;
        const float v = x[(size_t)row * IN_F + j] * coefj(j);
        const u16 h = f2bf(v);
        o = f2bf(v - bf2f(h));
      } else if (k < K_END) {
        const int j = k - K_HI1;
        o = f2bf(x[(size_t)row * IN_F + j] * coefj(j));
      } else {
        o = 0;
      }
      tmp[e] = o;
    }
    *(int4*)(Ab + (size_t)row * K_TOT + kb) = *(const int4*)tmp;
  }
}

// ---------------- packing: B = [bf16(W_non) | 0 | hi(W_nmda) | hi(W_nmda) | lo(W_nmda) | 0]
__global__ void pack_b_kernel(const float* __restrict__ Wnon,
                              const float* __restrict__ Wnmda,
                              u16* __restrict__ Bb) {
  const int units = OUT_F * (K_TOT / 8);
  for (int u = blockIdx.x * blockDim.x + threadIdx.x; u < units;
       u += gridDim.x * blockDim.x) {
    const int row = u / (K_TOT / 8);
    const int kb  = (u % (K_TOT / 8)) * 8;
    u16 tmp[8] __attribute__((aligned(16)));
#pragma unroll
    for (int e = 0; e < 8; ++e) {
      const int k = kb + e;
      u16 o;
      if (k < K_NON) {
        o = f2bf(Wnon[(size_t)row * K_NON + k]);
      } else if (k < K_HI0) {
        o = 0;
      } else if (k < K_LO0) {
        o = f2bf(Wnmda[(size_t)row * IC_N + (k - K_HI0)]);
      } else if (k < K_HI1) {
        o = f2bf(Wnmda[(size_t)row * IC_N + (k - K_LO0)]);
      } else if (k < K_END) {
        const float v = Wnmda[(size_t)row * IC_N + (k - K_HI1)];
        const u16 h = f2bf(v);
        o = f2bf(v - bf2f(h));
      } else {
        o = 0;
      }
      tmp[e] = o;
    }
    *(int4*)(Bb + (size_t)row * K_TOT + kb) = *(const int4*)tmp;
  }
}

// ---------------- fused GEMM: 256x256, BK=64, 8 waves, single-barrier read-ahead pipeline
#define GLOAD16(gp, lp)                                           \
  __builtin_amdgcn_global_load_lds(                               \
      (const __attribute__((address_space(1))) void*)(gp),        \
      (__attribute__((address_space(3))) void*)(lp), 16, 0, 0)

#define MEMFENCE() asm volatile("" ::: "memory")
#define BAR() do { MEMFENCE(); __builtin_amdgcn_s_barrier(); MEMFENCE(); } while (0)
#define LGKM0() asm volatile("s_waitcnt lgkmcnt(0)" ::: "memory")
#define VM6()   asm volatile("s_waitcnt vmcnt(6)" ::: "memory")
#define VM0()   asm volatile("s_waitcnt vmcnt(0)" ::: "memory")
#define VNONE   ((void)0)

// register-fragment loads (read-ahead: issued one phase before consumption)
#define RD_AF(SET, BW, KK, MH) do {                                    \
    _Pragma("unroll")                                                  \
    for (int mm = 0; mm < 4; ++mm)                                     \
      SET[mm] = *(const bf16x8*)(LDSc + (BW) * 65536 + (KK) * 16384 +  \
                 (wRow + (MH) * 64 + mm * 16) * 64 + laneOff);         \
  } while (0)
#define RD_BF(SET, BW, KK) do {                                        \
    _Pragma("unroll")                                                  \
    for (int n = 0; n < 4; ++n)                                        \
      SET[n] = *(const bf16x8*)(LDSc + (BW) * 65536 + 32768 +          \
                (KK) * 16384 + (wCol + n * 16) * 64 + laneOff);        \
  } while (0)

// Phase: drain own operand reads (issued last phase, ~free) -> issue next
// phase's reads + one slot refill -> 16 MFMA -> optional counted vmcnt -> BAR.
#define PHASE(AFC, BFC, MH, NEXT_READS, STAGE_STMT, VMSTMT) do {       \
    LGKM0();                                                           \
    NEXT_READS;                                                        \
    STAGE_STMT;                                                        \
    __builtin_amdgcn_sched_barrier(0);                                 \
    __builtin_amdgcn_s_setprio(1);                                     \
    _Pragma("unroll")                                                  \
    for (int mm = 0; mm < 4; ++mm)                                     \
      _Pragma("unroll")                                                \
      for (int n = 0; n < 4; ++n)                                      \
        acc[(MH) * 4 + mm][n] = __builtin_amdgcn_mfma_f32_16x16x32_bf16( \
            AFC[mm], BFC[n], acc[(MH) * 4 + mm][n], 0, 0, 0);          \
    __builtin_amdgcn_s_setprio(0);                                     \
    VMSTMT;                                                            \
    BAR();                                                             \
  } while (0)

__global__ __launch_bounds__(512, 1) void gemm_fused_kernel(
    const u16* __restrict__ Ab, const u16* __restrict__ Bb,
    const float* __restrict__ bnon, float* __restrict__ out) {
  // 8 slots of 16 KB: [buf][mat A/B][k-half]. Slot = 256 rows x 32 bf16.
  // phys = pair*128B + ((((row&1)<<2)|chunk16) ^ (pair&7))*16B  (involution)
  __shared__ __attribute__((aligned(16))) u16 LDSu[65536];
  char* LDSc = (char*)LDSu;

  const int bid = blockIdx.x;
  const int swz = ((bid & 7) << 6) | (bid >> 3);   // 512 % 8 == 0: bijective XCD swizzle
  const int bm = swz >> 4, bn = swz & 15;
  const int rowBase = bm * 256, colBase = bn * 256;

  const int tid  = threadIdx.x;
  const int w    = tid >> 6, lane = tid & 63;
  const int wm = w >> 2, wn = w & 3;               // 2 x 4 wave grid
  const int wRow = wm * 128, wCol = wn * 64;       // per-wave 128x64 output
  const int l15 = lane & 15, g = lane >> 4;

  // per-lane swizzled read offset (constant across fragments; R*64 adds cleanly)
  const int laneOff = ((l15 >> 1) << 7) +
                      (((((l15 & 1) << 2) | g) ^ ((l15 >> 1) & 7)) << 4);

  // staging: linear LDS dest (d = issue*8192 + tid*16), inverse-swizzled global src
  int rowS[2], colS[2];
#pragma unroll
  for (int is = 0; is < 2; ++is) {
    const int d = is * 8192 + tid * 16;
    const int b = d ^ ((d >> 3) & 0x70);
    rowS[is] = ((b >> 7) << 1) | ((b >> 6) & 1);
    colS[is] = (b >> 1) & 31;
  }
  const u16* pA0 = Ab + (size_t)(rowBase + rowS[0]) * K_TOT + colS[0];
  const u16* pA1 = Ab + (size_t)(rowBase + rowS[1]) * K_TOT + colS[1];
  const u16* pB0 = Bb + (size_t)(colBase + rowS[0]) * K_TOT + colS[0];
  const u16* pB1 = Bb + (size_t)(colBase + rowS[1]) * K_TOT + colS[1];

  // bias: load, keep alive, and fully retire so the vmcnt ledger stays clean
  float bn4[4];
#pragma unroll
  for (int n = 0; n < 4; ++n) bn4[n] = bnon[colBase + wCol + n * 16 + l15];
  asm volatile("" :: "v"(bn4[0]), "v"(bn4[1]), "v"(bn4[2]), "v"(bn4[3]));
  VM0();

  auto stageU = [&](int mat, int buf, int ks, int t64) {
    const u16* s0 = (mat ? pB0 : pA0) + t64 + ks * 32;
    const u16* s1 = (mat ? pB1 : pA1) + t64 + ks * 32;
    char* dst = LDSc + buf * 65536 + mat * 32768 + ks * 16384 + tid * 16;
    GLOAD16(s0, dst);
    GLOAD16(s1, dst + 8192);
  };

  f32x4 acc[8][4] = {};
  bf16x8 afA[4], afB[4], bfrA[4], bfrB[4];

  // prologue: tile0 full (buf0) + tile1 k0 (buf1) = 12 gloads; retire first 4
  stageU(0, 0, 0, 0); stageU(1, 0, 0, 0);          // (0,A,k0) (0,B,k0)
  stageU(0, 0, 1, 0); stageU(1, 0, 1, 0);          // (0,A,k1) (0,B,k1)
  stageU(0, 1, 0, 64); stageU(1, 1, 0, 64);        // (1,A,k0) (1,B,k0)  tile 1
  asm volatile("s_waitcnt vmcnt(8)" ::: "memory"); // (0,*,k0) resident
  BAR();
  RD_BF(bfrA, 0, 0); RD_AF(afA, 0, 0, 0);          // p0 operands

  for (int T = 0; T < NT - 2; T += 2) {
    if (T == T_SPLIT) {
      // acc == x_nc @ W_non^T complete; in-place: sigmoid(acc+b) - 1
#pragma unroll
      for (int m = 0; m < 8; ++m)
#pragma unroll
        for (int n = 0; n < 4; ++n)
#pragma unroll
          for (int j = 0; j < 4; ++j) {
            const float t = acc[m][n][j] + bn4[n];
            acc[m][n][j] = 1.0f / (1.0f + __expf(-t)) - 1.0f;
          }
    }
    const int t1 = (T + 1) * 64, t2 = (T + 2) * 64, t3 = (T + 3) * 64;
    // p0..p3: buf0 (tile T); p4..p7: buf1 (tile T+1). Reads lead by 1 phase.
    PHASE(afA, bfrA, 0, RD_AF(afB, 0, 0, 1),                           stageU(0, 1, 1, t1), VM6());
    PHASE(afB, bfrA, 1, { RD_BF(bfrB, 0, 1); RD_AF(afA, 0, 1, 0); },   stageU(1, 1, 1, t1), VNONE);
    PHASE(afA, bfrB, 0, RD_AF(afB, 0, 1, 1),                           stageU(0, 0, 0, t2), VM6());
    PHASE(afB, bfrB, 1, { RD_BF(bfrA, 1, 0); RD_AF(afA, 1, 0, 0); },   stageU(1, 0, 0, t2), VNONE);
    PHASE(afA, bfrA, 0, RD_AF(afB, 1, 0, 1),                           stageU(0, 0, 1, t2), VM6());
    PHASE(afB, bfrA, 1, { RD_BF(bfrB, 1, 1); RD_AF(afA, 1, 1, 0); },   stageU(1, 0, 1, t2), VNONE);
    PHASE(afA, bfrB, 0, RD_AF(afB, 1, 1, 1),                           stageU(0, 1, 0, t3), VM6());
    PHASE(afB, bfrB, 1, { RD_BF(bfrA, 0, 0); RD_AF(afA, 0, 0, 0); },   stageU(1, 1, 0, t3), VNONE);
  }

  {   // tail body T = NT-2: no further buf0/next-buf1 staging; full drains
    const int t1 = (NT - 1) * 64;
    PHASE(afA, bfrA, 0, RD_AF(afB, 0, 0, 1),                           stageU(0, 1, 1, t1), VM0());
    PHASE(afB, bfrA, 1, { RD_BF(bfrB, 0, 1); RD_AF(afA, 0, 1, 0); },   stageU(1, 1, 1, t1), VNONE);
    PHASE(afA, bfrB, 0, RD_AF(afB, 0, 1, 1),                           VNONE,               VM0());
    PHASE(afB, bfrB, 1, { RD_BF(bfrA, 1, 0); RD_AF(afA, 1, 0, 0); },   VNONE,               VNONE);
    PHASE(afA, bfrA, 0, RD_AF(afB, 1, 0, 1),                           VNONE,               VM0());
    PHASE(afB, bfrA, 1, { RD_BF(bfrB, 1, 1); RD_AF(afA, 1, 1, 0); },   VNONE,               VNONE);
    PHASE(afA, bfrB, 0, RD_AF(afB, 1, 1, 1),                           VNONE,               VM0());
    PHASE(afB, bfrB, 1, VNONE,                                         VNONE,               VNONE);
  }

  // epilogue: Hill. C/D layout col=lane&15, row=(lane>>4)*4+j  [m89/m91]
#pragma unroll
  for (int m = 0; m < 8; ++m) {
#pragma unroll
    for (int n = 0; n < 4; ++n) {
#pragma unroll
      for (int j = 0; j < 4; ++j) {
        const int r = rowBase + wRow + m * 16 + g * 4 + j;
        const int c = colBase + wCol + n * 16 + l15;
        const float pre = acc[m][n][j];
        const float xn = pre * pre;
        out[(size_t)r * OUT_F + c] = xn / (0.25f + xn);
      }
    }
  }
}

// ---------------- fallback (workspace too small): naive fp32
__global__ void naive_fused_kernel(const float* __restrict__ x,
                                   const float* __restrict__ Wnmda,
                                   const float* __restrict__ Wnon,
                                   const float* __restrict__ bnon,
                                   float* __restrict__ out) {
  const long long total = (long long)BATCHN * OUT_F;
  for (long long idx = (long long)blockIdx.x * blockDim.x + threadIdx.x;
       idx < total; idx += (long long)gridDim.x * blockDim.x) {
    const int b = (int)(idx / OUT_F);
    const int o = (int)(idx % OUT_F);
    float s = bnon[o];
    for (int k = 0; k < K_NON; ++k)
      s += x[(size_t)b * IN_F + IC_N + k] * Wnon[(size_t)o * K_NON + k];
    const float state = 1.0f / (1.0f + __expf(-s)) - 1.0f;
    float ca = 0.0f;
    for (int j = 0; j < IC_N; ++j)
      ca += x[(size_t)b * IN_F + j] * coefj(j) * Wnmda[(size_t)o * IC_N + j];
    const float pre = ca + state;
    const float xn = pre * pre;
    out[idx] = xn / (0.25f + xn);
  }
}

extern "C" void kernel_launch(void* const* d_in, const int* in_sizes, int n_in,
                              void* d_out, int out_size, void* d_ws, size_t ws_size,
                              hipStream_t stream) {
  const float* x     = (const float*)d_in[0];
  const float* Wnmda = (const float*)d_in[1];
  const float* Wnon  = (const float*)d_in[2];
  const float* bnon  = (const float*)d_in[3];
  float* out = (float*)d_out;

  const size_t needA = (size_t)BATCHN * K_TOT * sizeof(u16);  // ~81.8 MB
  const size_t needB = (size_t)OUT_F * K_TOT * sizeof(u16);   // ~40.9 MB

  if (ws_size < needA + needB) {
    naive_fused_kernel<<<8192, 256, 0, stream>>>(x, Wnmda, Wnon, bnon, out);
    return;
  }

  u16* Ab = (u16*)d_ws;
  u16* Bb = Ab + (size_t)BATCHN * K_TOT;

  pack_a_kernel<<<2048, 256, 0, stream>>>(x, Ab);
  pack_b_kernel<<<1024, 256, 0, stream>>>(Wnon, Wnmda, Bb);
  gemm_fused_kernel<<<512, 512, 0, stream>>>(Ab, Bb, bnon, out);
}

// Round 5
// 358.721 us; speedup vs baseline: 1.4561x; 1.2166x over previous
//
#include <hip/hip_runtime.h>
#include <hip/hip_bf16.h>
#include <cstdint>
#include <cstddef>

typedef unsigned short u16;
typedef __bf16 bf16x8 __attribute__((ext_vector_type(8)));
typedef float f32x4 __attribute__((ext_vector_type(4)));
typedef float f32x4u __attribute__((ext_vector_type(4), aligned(4)));  // 4B-aligned vector load

#define IN_F   4096
#define OUT_F  4096
#define IC_N   409      // int(4096*0.1)
#define K_NON  3687     // 4096-409
#define K_HI0  3712     // 58*64: sigmoid boundary (BK-aligned)
#define K_LO0  4121
#define K_HI1  4530
#define K_END  4939
#define K_TOT  4992     // 78*64
#define BATCHN 8192
#define NT     78       // K-tiles of 64
#define T_SPLIT 58      // body index where state transform applies

__device__ __forceinline__ u16 f2bf(float f) {          // RNE fp32->bf16
  uint32_t u = __float_as_uint(f);
  uint32_t r = (u + 0x7FFFu + ((u >> 16) & 1u)) >> 16;
  return (u16)r;
}
__device__ __forceinline__ float bf2f(u16 h) {
  return __uint_as_float(((uint32_t)h) << 16);
}
__device__ __forceinline__ float coefj(int j) {
  return (j == 0 || j == IC_N - 1) ? 1.0f : 2.0f;
}

// ---------------- pack A: one block per batch row. Layout:
// [bf16(x_nc) 0..3686 | 0 | hi(xc*c) 3712.. | lo(xc*c) 4121.. | hi(xc*c) 4530.. | 0]
__global__ __launch_bounds__(256) void pack_a_kernel(const float* __restrict__ x,
                                                     u16* __restrict__ Ab) {
  __shared__ u16 hbuf[IC_N];
  __shared__ u16 lbuf[IC_N];
  const int row = blockIdx.x;
  const float* xr = x + (size_t)row * IN_F;
  // cluster hi/lo split, computed once per row
  for (int j = threadIdx.x; j < IC_N; j += 256) {
    const float v = xr[j] * coefj(j);
    const u16 h = f2bf(v);
    hbuf[j] = h;
    lbuf[j] = f2bf(v - bf2f(h));
  }
  __syncthreads();
  u16* outr = Ab + (size_t)row * K_TOT;
  for (int c8 = threadIdx.x; c8 < K_TOT / 8; c8 += 256) {
    const int kb = c8 * 8;
    u16 tmp[8] __attribute__((aligned(16)));
    if (kb + 8 <= K_NON) {                       // pure x_nc chunk: vector loads
      const float* s = xr + IC_N + kb;
      const f32x4u v0 = *(const f32x4u*)s;
      const f32x4u v1 = *(const f32x4u*)(s + 4);
#pragma unroll
      for (int e = 0; e < 4; ++e) { tmp[e] = f2bf(v0[e]); tmp[4 + e] = f2bf(v1[e]); }
    } else if (kb < K_HI0) {                     // boundary / zero-pad chunks
#pragma unroll
      for (int e = 0; e < 8; ++e) {
        const int k = kb + e;
        tmp[e] = (k < K_NON) ? f2bf(xr[IC_N + k]) : (u16)0;
      }
    } else {                                     // cluster region: gather from LDS
#pragma unroll
      for (int e = 0; e < 8; ++e) {
        const int k = kb + e;
        u16 o;
        if (k < K_LO0)      o = hbuf[k - K_HI0];
        else if (k < K_HI1) o = lbuf[k - K_LO0];
        else if (k < K_END) o = hbuf[k - K_HI1];
        else                o = 0;
        tmp[e] = o;
      }
    }
    *(int4*)(outr + kb) = *(const int4*)tmp;
  }
}

// ---------------- pack B: one block per output row. Layout:
// [bf16(W_non) | 0 | hi(W_nmda) | hi(W_nmda) | lo(W_nmda) | 0]
__global__ __launch_bounds__(256) void pack_b_kernel(const float* __restrict__ Wnon,
                                                     const float* __restrict__ Wnmda,
                                                     u16* __restrict__ Bb) {
  __shared__ u16 hbuf[IC_N];
  __shared__ u16 lbuf[IC_N];
  const int row = blockIdx.x;
  const float* wr = Wnon + (size_t)row * K_NON;
  const float* wc = Wnmda + (size_t)row * IC_N;
  for (int j = threadIdx.x; j < IC_N; j += 256) {
    const float v = wc[j];
    const u16 h = f2bf(v);
    hbuf[j] = h;
    lbuf[j] = f2bf(v - bf2f(h));
  }
  __syncthreads();
  u16* outr = Bb + (size_t)row * K_TOT;
  for (int c8 = threadIdx.x; c8 < K_TOT / 8; c8 += 256) {
    const int kb = c8 * 8;
    u16 tmp[8] __attribute__((aligned(16)));
    if (kb + 8 <= K_NON) {
      const float* s = wr + kb;
      const f32x4u v0 = *(const f32x4u*)s;
      const f32x4u v1 = *(const f32x4u*)(s + 4);
#pragma unroll
      for (int e = 0; e < 4; ++e) { tmp[e] = f2bf(v0[e]); tmp[4 + e] = f2bf(v1[e]); }
    } else if (kb < K_HI0) {
#pragma unroll
      for (int e = 0; e < 8; ++e) {
        const int k = kb + e;
        tmp[e] = (k < K_NON) ? f2bf(wr[k]) : (u16)0;
      }
    } else {
#pragma unroll
      for (int e = 0; e < 8; ++e) {
        const int k = kb + e;
        u16 o;
        if (k < K_LO0)      o = hbuf[k - K_HI0];
        else if (k < K_HI1) o = hbuf[k - K_LO0];
        else if (k < K_END) o = lbuf[k - K_HI1];
        else                o = 0;
        tmp[e] = o;
      }
    }
    *(int4*)(outr + kb) = *(const int4*)tmp;
  }
}

// ---------------- fused GEMM: 256x256, BK=64, 8 waves, single-barrier read-ahead pipeline
// (byte-identical to round-4 verified kernel)
#define GLOAD16(gp, lp)                                           \
  __builtin_amdgcn_global_load_lds(                               \
      (const __attribute__((address_space(1))) void*)(gp),        \
      (__attribute__((address_space(3))) void*)(lp), 16, 0, 0)

#define MEMFENCE() asm volatile("" ::: "memory")
#define BAR() do { MEMFENCE(); __builtin_amdgcn_s_barrier(); MEMFENCE(); } while (0)
#define LGKM0() asm volatile("s_waitcnt lgkmcnt(0)" ::: "memory")
#define VM6()   asm volatile("s_waitcnt vmcnt(6)" ::: "memory")
#define VM0()   asm volatile("s_waitcnt vmcnt(0)" ::: "memory")
#define VNONE   ((void)0)

#define RD_AF(SET, BW, KK, MH) do {                                    \
    _Pragma("unroll")                                                  \
    for (int mm = 0; mm < 4; ++mm)                                     \
      SET[mm] = *(const bf16x8*)(LDSc + (BW) * 65536 + (KK) * 16384 +  \
                 (wRow + (MH) * 64 + mm * 16) * 64 + laneOff);         \
  } while (0)
#define RD_BF(SET, BW, KK) do {                                        \
    _Pragma("unroll")                                                  \
    for (int n = 0; n < 4; ++n)                                        \
      SET[n] = *(const bf16x8*)(LDSc + (BW) * 65536 + 32768 +          \
                (KK) * 16384 + (wCol + n * 16) * 64 + laneOff);        \
  } while (0)

#define PHASE(AFC, BFC, MH, NEXT_READS, STAGE_STMT, VMSTMT) do {       \
    LGKM0();                                                           \
    NEXT_READS;                                                        \
    STAGE_STMT;                                                        \
    __builtin_amdgcn_sched_barrier(0);                                 \
    __builtin_amdgcn_s_setprio(1);                                     \
    _Pragma("unroll")                                                  \
    for (int mm = 0; mm < 4; ++mm)                                     \
      _Pragma("unroll")                                                \
      for (int n = 0; n < 4; ++n)                                      \
        acc[(MH) * 4 + mm][n] = __builtin_amdgcn_mfma_f32_16x16x32_bf16( \
            AFC[mm], BFC[n], acc[(MH) * 4 + mm][n], 0, 0, 0);          \
    __builtin_amdgcn_s_setprio(0);                                     \
    VMSTMT;                                                            \
    BAR();                                                             \
  } while (0)

__global__ __launch_bounds__(512, 1) void gemm_fused_kernel(
    const u16* __restrict__ Ab, const u16* __restrict__ Bb,
    const float* __restrict__ bnon, float* __restrict__ out) {
  // 8 slots of 16 KB: [buf][mat A/B][k-half]. Slot = 256 rows x 32 bf16.
  // phys = pair*128B + ((((row&1)<<2)|chunk16) ^ (pair&7))*16B  (involution)
  __shared__ __attribute__((aligned(16))) u16 LDSu[65536];
  char* LDSc = (char*)LDSu;

  const int bid = blockIdx.x;
  const int swz = ((bid & 7) << 6) | (bid >> 3);   // 512 % 8 == 0: bijective XCD swizzle
  const int bm = swz >> 4, bn = swz & 15;
  const int rowBase = bm * 256, colBase = bn * 256;

  const int tid  = threadIdx.x;
  const int w    = tid >> 6, lane = tid & 63;
  const int wm = w >> 2, wn = w & 3;               // 2 x 4 wave grid
  const int wRow = wm * 128, wCol = wn * 64;       // per-wave 128x64 output
  const int l15 = lane & 15, g = lane >> 4;

  const int laneOff = ((l15 >> 1) << 7) +
                      (((((l15 & 1) << 2) | g) ^ ((l15 >> 1) & 7)) << 4);

  int rowS[2], colS[2];
#pragma unroll
  for (int is = 0; is < 2; ++is) {
    const int d = is * 8192 + tid * 16;
    const int b = d ^ ((d >> 3) & 0x70);
    rowS[is] = ((b >> 7) << 1) | ((b >> 6) & 1);
    colS[is] = (b >> 1) & 31;
  }
  const u16* pA0 = Ab + (size_t)(rowBase + rowS[0]) * K_TOT + colS[0];
  const u16* pA1 = Ab + (size_t)(rowBase + rowS[1]) * K_TOT + colS[1];
  const u16* pB0 = Bb + (size_t)(colBase + rowS[0]) * K_TOT + colS[0];
  const u16* pB1 = Bb + (size_t)(colBase + rowS[1]) * K_TOT + colS[1];

  float bn4[4];
#pragma unroll
  for (int n = 0; n < 4; ++n) bn4[n] = bnon[colBase + wCol + n * 16 + l15];
  asm volatile("" :: "v"(bn4[0]), "v"(bn4[1]), "v"(bn4[2]), "v"(bn4[3]));
  VM0();

  auto stageU = [&](int mat, int buf, int ks, int t64) {
    const u16* s0 = (mat ? pB0 : pA0) + t64 + ks * 32;
    const u16* s1 = (mat ? pB1 : pA1) + t64 + ks * 32;
    char* dst = LDSc + buf * 65536 + mat * 32768 + ks * 16384 + tid * 16;
    GLOAD16(s0, dst);
    GLOAD16(s1, dst + 8192);
  };

  f32x4 acc[8][4] = {};
  bf16x8 afA[4], afB[4], bfrA[4], bfrB[4];

  // prologue: tile0 full (buf0) + tile1 k0 (buf1) = 12 gloads
  stageU(0, 0, 0, 0); stageU(1, 0, 0, 0);
  stageU(0, 0, 1, 0); stageU(1, 0, 1, 0);
  stageU(0, 1, 0, 64); stageU(1, 1, 0, 64);
  asm volatile("s_waitcnt vmcnt(8)" ::: "memory"); // (0,*,k0) resident
  BAR();
  RD_BF(bfrA, 0, 0); RD_AF(afA, 0, 0, 0);          // p0 operands

  for (int T = 0; T < NT - 2; T += 2) {
    if (T == T_SPLIT) {
      // acc == x_nc @ W_non^T complete; in-place: sigmoid(acc+b) - 1
#pragma unroll
      for (int m = 0; m < 8; ++m)
#pragma unroll
        for (int n = 0; n < 4; ++n)
#pragma unroll
          for (int j = 0; j < 4; ++j) {
            const float t = acc[m][n][j] + bn4[n];
            acc[m][n][j] = 1.0f / (1.0f + __expf(-t)) - 1.0f;
          }
    }
    const int t1 = (T + 1) * 64, t2 = (T + 2) * 64, t3 = (T + 3) * 64;
    PHASE(afA, bfrA, 0, RD_AF(afB, 0, 0, 1),                           stageU(0, 1, 1, t1), VM6());
    PHASE(afB, bfrA, 1, { RD_BF(bfrB, 0, 1); RD_AF(afA, 0, 1, 0); },   stageU(1, 1, 1, t1), VNONE);
    PHASE(afA, bfrB, 0, RD_AF(afB, 0, 1, 1),                           stageU(0, 0, 0, t2), VM6());
    PHASE(afB, bfrB, 1, { RD_BF(bfrA, 1, 0); RD_AF(afA, 1, 0, 0); },   stageU(1, 0, 0, t2), VNONE);
    PHASE(afA, bfrA, 0, RD_AF(afB, 1, 0, 1),                           stageU(0, 0, 1, t2), VM6());
    PHASE(afB, bfrA, 1, { RD_BF(bfrB, 1, 1); RD_AF(afA, 1, 1, 0); },   stageU(1, 0, 1, t2), VNONE);
    PHASE(afA, bfrB, 0, RD_AF(afB, 1, 1, 1),                           stageU(0, 1, 0, t3), VM6());
    PHASE(afB, bfrB, 1, { RD_BF(bfrA, 0, 0); RD_AF(afA, 0, 0, 0); },   stageU(1, 1, 0, t3), VNONE);
  }

  {   // tail body T = NT-2
    const int t1 = (NT - 1) * 64;
    PHASE(afA, bfrA, 0, RD_AF(afB, 0, 0, 1),                           stageU(0, 1, 1, t1), VM0());
    PHASE(afB, bfrA, 1, { RD_BF(bfrB, 0, 1); RD_AF(afA, 0, 1, 0); },   stageU(1, 1, 1, t1), VNONE);
    PHASE(afA, bfrB, 0, RD_AF(afB, 0, 1, 1),                           VNONE,               VM0());
    PHASE(afB, bfrB, 1, { RD_BF(bfrA, 1, 0); RD_AF(afA, 1, 0, 0); },   VNONE,               VNONE);
    PHASE(afA, bfrA, 0, RD_AF(afB, 1, 0, 1),                           VNONE,               VM0());
    PHASE(afB, bfrA, 1, { RD_BF(bfrB, 1, 1); RD_AF(afA, 1, 1, 0); },   VNONE,               VNONE);
    PHASE(afA, bfrB, 0, RD_AF(afB, 1, 1, 1),                           VNONE,               VM0());
    PHASE(afB, bfrB, 1, VNONE,                                         VNONE,               VNONE);
  }

  // epilogue: Hill. C/D layout col=lane&15, row=(lane>>4)*4+j  [m89/m91]
#pragma unroll
  for (int m = 0; m < 8; ++m) {
#pragma unroll
    for (int n = 0; n < 4; ++n) {
#pragma unroll
      for (int j = 0; j < 4; ++j) {
        const int r = rowBase + wRow + m * 16 + g * 4 + j;
        const int c = colBase + wCol + n * 16 + l15;
        const float pre = acc[m][n][j];
        const float xn = pre * pre;
        out[(size_t)r * OUT_F + c] = xn / (0.25f + xn);
      }
    }
  }
}

// ---------------- fallback (workspace too small): naive fp32
__global__ void naive_fused_kernel(const float* __restrict__ x,
                                   const float* __restrict__ Wnmda,
                                   const float* __restrict__ Wnon,
                                   const float* __restrict__ bnon,
                                   float* __restrict__ out) {
  const long long total = (long long)BATCHN * OUT_F;
  for (long long idx = (long long)blockIdx.x * blockDim.x + threadIdx.x;
       idx < total; idx += (long long)gridDim.x * blockDim.x) {
    const int b = (int)(idx / OUT_F);
    const int o = (int)(idx % OUT_F);
    float s = bnon[o];
    for (int k = 0; k < K_NON; ++k)
      s += x[(size_t)b * IN_F + IC_N + k] * Wnon[(size_t)o * K_NON + k];
    const float state = 1.0f / (1.0f + __expf(-s)) - 1.0f;
    float ca = 0.0f;
    for (int j = 0; j < IC_N; ++j)
      ca += x[(size_t)b * IN_F + j] * coefj(j) * Wnmda[(size_t)o * IC_N + j];
    const float pre = ca + state;
    const float xn = pre * pre;
    out[idx] = xn / (0.25f + xn);
  }
}

extern "C" void kernel_launch(void* const* d_in, const int* in_sizes, int n_in,
                              void* d_out, int out_size, void* d_ws, size_t ws_size,
                              hipStream_t stream) {
  const float* x     = (const float*)d_in[0];
  const float* Wnmda = (const float*)d_in[1];
  const float* Wnon  = (const float*)d_in[2];
  const float* bnon  = (const float*)d_in[3];
  float* out = (float*)d_out;

  const size_t needA = (size_t)BATCHN * K_TOT * sizeof(u16);  // ~81.8 MB
  const size_t needB = (size_t)OUT_F * K_TOT * sizeof(u16);   // ~40.9 MB

  if (ws_size < needA + needB) {
    naive_fused_kernel<<<8192, 256, 0, stream>>>(x, Wnmda, Wnon, bnon, out);
    return;
  }

  u16* Ab = (u16*)d_ws;
  u16* Bb = Ab + (size_t)BATCHN * K_TOT;

  pack_a_kernel<<<BATCHN, 256, 0, stream>>>(x, Ab);
  pack_b_kernel<<<OUT_F, 256, 0, stream>>>(Wnon, Wnmda, Bb);
  gemm_fused_kernel<<<512, 512, 0, stream>>>(Ab, Bb, bnon, out);
}